// Round 4
// baseline (1082.069 us; speedup 1.0000x reference)
//
#include <hip/hip_runtime.h>
#include <cstdint>
#include <cstddef>

// RNNDec GRU rollout: N=4096, H=512, T=12. R4: fp16 single-plane MFMA
// (half the MFMA/bytes of bf16 hi+lo, better precision) + ONE persistent
// kernel for all 12 steps: h-slice LDS-resident per block, W_hh streamed
// through dbuf LDS chunks, manual 2-level grid barrier between steps.
// Block = 64 rows x (128 jc x 3 gates); 256 blocks = 1/CU (LDS-forced).

typedef __attribute__((ext_vector_type(8))) _Float16 f16x8;
typedef __attribute__((ext_vector_type(16))) float floatx16;

__device__ __forceinline__ float sigm_f(float v) { return 1.0f / (1.0f + __expf(-v)); }
__device__ __forceinline__ float tanh_f(float v) { return 2.0f / (1.0f + __expf(-2.0f * v)) - 1.0f; }

__device__ __forceinline__ void async16(void* lds, const void* g) {
    __builtin_amdgcn_global_load_lds(
        (const __attribute__((address_space(1))) void*)g,
        (__attribute__((address_space(3))) void*)lds, 16, 0, 0);
}

// ---------------- K0: casts + packing + a0 ----------------
__global__ __launch_bounds__(256) void k0_prep(
    const float* __restrict__ z, const float* __restrict__ x,
    const float* __restrict__ x0, const float* __restrict__ W_ia,
    const float* __restrict__ b_ia, const float* __restrict__ W_ih,
    const float* __restrict__ W_hh, const float* __restrict__ W_h0,
    const float* __restrict__ W_out, const float* __restrict__ b_hh,
    _Float16* __restrict__ zx16, _Float16* __restrict__ wcat16,
    _Float16* __restrict__ whh16, float* __restrict__ pk, float* __restrict__ xbuf)
{
    const int ZX = 4096 * 256, WC = 2048 * 256, WH = 1536 * 512, PKN = 512, XB = 4096 * 2;
    const int total = ZX + WC + WH + PKN + XB;
    for (int idx = blockIdx.x * 256 + threadIdx.x; idx < total; idx += gridDim.x * 256) {
        if (idx < ZX) {
            int i = idx >> 8, k = idx & 255;
            float v = (k < 128) ? z[i * 128 + k] : x[i * 128 + (k - 128)];
            zx16[idx] = (_Float16)v;
        } else if (idx < ZX + WC) {
            int j = idx - ZX;
            int n = j >> 8, k = j & 255;
            float v = (n < 512) ? W_h0[n * 256 + k] : W_ih[(n - 512) * 258 + k];
            wcat16[j] = (_Float16)v;
        } else if (idx < ZX + WC + WH) {
            int j = idx - ZX - WC;
            whh16[j] = (_Float16)W_hh[j];
        } else if (idx < ZX + WC + WH + PKN) {
            int jc = idx - ZX - WC - WH;
            float* o = pk + jc * 12;
            o[0] = W_ih[jc * 258 + 256];          o[1] = W_ih[jc * 258 + 257];
            o[2] = W_ih[(512 + jc) * 258 + 256];  o[3] = W_ih[(512 + jc) * 258 + 257];
            o[4] = W_ih[(1024 + jc) * 258 + 256]; o[5] = W_ih[(1024 + jc) * 258 + 257];
            o[6] = b_hh[jc]; o[7] = b_hh[512 + jc]; o[8] = b_hh[1024 + jc];
            o[9] = W_out[jc]; o[10] = W_out[512 + jc]; o[11] = 0.f;
        } else {
            int j = idx - ZX - WC - WH - PKN;
            int i = j >> 1, d = j & 1;
            float s = b_ia[d];
            #pragma unroll
            for (int k2 = 0; k2 < 4; k2++) s += x0[i * 4 + k2] * W_ia[d * 4 + k2];
            xbuf[j] = s;
        }
    }
}

// ---------------- K1: h0 (cols 0..511) + gi_base (cols 512..2047), fp16 ----------------
// C[4096 x 2048] = zx16 @ wcat16^T, K=256. Tile 128m x 64n, BK=64, 4 chunks.
__global__ __launch_bounds__(256) void k1_precompute(
    const _Float16* __restrict__ zx16, const _Float16* __restrict__ wcat16,
    const float* __restrict__ b_h0, const float* __restrict__ b_ih,
    _Float16* __restrict__ h16a, float* __restrict__ gi2)
{
    __shared__ __align__(16) char smem[24576];
    const uint32_t BOFF = 0, AOFF = 8192;
    int tid = threadIdx.x;
    int w = tid >> 6, lane = tid & 63;
    int half = lane >> 5, l31 = lane & 31;
    int rsub = lane >> 3, csub = lane & 7;
    int Mb = blockIdx.x * 128, Nb = blockIdx.y * 64;

    const _Float16* gsrc[6];
    uint32_t ldso[6];
    #pragma unroll
    for (int j = 0; j < 6; j++) {
        int L = w + 4 * j;
        if (L < 16) {
            int r = L * 8 + rsub;
            gsrc[j] = zx16 + (size_t)(Mb + r) * 256 + ((csub ^ (r & 7)) << 3);
            ldso[j] = AOFF + (uint32_t)L * 1024;
        } else {
            int rb = (L - 16) * 8 + rsub;
            gsrc[j] = wcat16 + (size_t)(Nb + rb) * 256 + ((csub ^ (rb & 7)) << 3);
            ldso[j] = BOFF + (uint32_t)(L - 16) * 1024;
        }
    }

    floatx16 acc0 = {0,0,0,0,0,0,0,0,0,0,0,0,0,0,0,0};
    floatx16 acc1 = {0,0,0,0,0,0,0,0,0,0,0,0,0,0,0,0};

    #pragma unroll
    for (int j = 0; j < 6; j++) async16(smem + ldso[j], gsrc[j]);
    for (int kc = 0; kc < 4; kc++) {
        __syncthreads();
        #pragma unroll
        for (int ks = 0; ks < 4; ks++) {
            int ch = ks * 2 + half;
            int ar = (w << 5) | l31;
            f16x8 a = *(const f16x8*)(smem + AOFF + ((uint32_t)ar << 7) + ((uint32_t)(ch ^ (ar & 7)) << 4));
            uint32_t sw = (uint32_t)(ch ^ (l31 & 7)) << 4;
            f16x8 b0 = *(const f16x8*)(smem + BOFF + ((uint32_t)l31 << 7) + sw);
            f16x8 b1 = *(const f16x8*)(smem + BOFF + ((uint32_t)(32 + l31) << 7) + sw);
            acc0 = __builtin_amdgcn_mfma_f32_32x32x16_f16(a, b0, acc0, 0, 0, 0);
            acc1 = __builtin_amdgcn_mfma_f32_32x32x16_f16(a, b1, acc1, 0, 0, 0);
        }
        __syncthreads();
        if (kc < 3) {
            #pragma unroll
            for (int j = 0; j < 6; j++) async16(smem + ldso[j], gsrc[j] + (kc + 1) * 64);
        }
    }

    #pragma unroll
    for (int nt = 0; nt < 2; nt++) {
        int ncol = Nb + nt * 32 + l31;
        floatx16 acc = nt ? acc1 : acc0;
        #pragma unroll
        for (int reg = 0; reg < 16; reg++) {
            int row = (reg & 3) + 8 * (reg >> 2) + 4 * half;
            size_t i = (size_t)Mb + (w << 5) + row;
            float v = acc[reg];
            if (ncol < 512) {
                h16a[i * 512 + ncol] = (_Float16)(v + b_h0[ncol]);
            } else {
                int c = ncol - 512;
                int g = c >> 9, jc = c & 511;
                gi2[((size_t)i * 512 + jc) * 3 + g] = v + b_ih[c];
            }
        }
    }
}

// ---------------- grid barrier (2-level, agent-scope atomics) ----------------
__device__ __forceinline__ void grid_barrier(unsigned* grp, unsigned* root, int phase, int bid) {
    __syncthreads();
    if (threadIdx.x == 0) {
        unsigned g = (unsigned)(bid >> 4);
        unsigned v = __hip_atomic_fetch_add(&grp[phase * 16 + g], 1u,
                                            __ATOMIC_ACQ_REL, __HIP_MEMORY_SCOPE_AGENT);
        if (v == 15u)
            __hip_atomic_fetch_add(&root[phase], 1u, __ATOMIC_ACQ_REL, __HIP_MEMORY_SCOPE_AGENT);
        while (__hip_atomic_load(&root[phase], __ATOMIC_ACQUIRE, __HIP_MEMORY_SCOPE_AGENT) < 16u)
            __builtin_amdgcn_s_sleep(4);
    }
    __syncthreads();
}

// ---------------- K2: all 12 GRU steps, persistent ----------------
// 256 blocks x 256 thr. Block (bxg=bid&63, ng=bid>>6): rows R=bxg*64, jc J=ng*128.
// LDS: hA[64][512] f16 (XOR-swizzled 16B granules) + B dbuf 2x(384x64B) + xs + part4.
__global__ __launch_bounds__(256, 1) void k2_all(
    const _Float16* __restrict__ whh16, const float* __restrict__ gi2,
    const float* __restrict__ pk, const float* __restrict__ xbuf,
    _Float16* __restrict__ h16a, _Float16* __restrict__ h16b,
    float* __restrict__ partial, float* __restrict__ dout,
    const float* __restrict__ b_out, unsigned* __restrict__ bars)
{
    extern __shared__ __align__(16) char smem[];
    const uint32_t HA = 0;          // 64*1024 = 65536
    const uint32_t BOFF = 65536;    // 2 * 24576 = 49152
    const uint32_t XS = 114688;     // 64*2*4 = 512
    const uint32_t P4 = 115200;     // 64*2*4*4 = 2048
    int tid = threadIdx.x, bid = blockIdx.x;
    int w = tid >> 6, lane = tid & 63, l31 = lane & 31, half = lane >> 5;
    int bxg = bid & 63, ng = bid >> 6;
    int R = bxg * 64, J = ng * 128;
    int jcg = J + w * 32 + l31;
    float* xs = (float*)(smem + XS);
    float* part4 = (float*)(smem + P4);
    unsigned* grp = bars;
    unsigned* root = bars + 12 * 16;

    // per-thread constants
    const float4* pkp = (const float4*)(pk + (size_t)jcg * 12);
    float4 p0 = pkp[0], p1 = pkp[1], p2 = pkp[2];
    // p0={wxr0,wxr1,wxz0,wxz1} p1={wxn0,wxn1,bhr,bhz} p2={bhn,wo0,wo1,-}

    // B staging sources (constant across steps): issue e = w+4j, rows br=e*16+(lane>>2)
    const _Float16* srcB[6];
    uint32_t dstB[6];
    #pragma unroll
    for (int j = 0; j < 6; j++) {
        int e = w + 4 * j;
        int br = e * 16 + (lane >> 2);
        int g = br >> 7, jj = br & 127;
        int g4s = (lane & 3) ^ ((br >> 1) & 3);
        srcB[j] = whh16 + (size_t)(g * 512 + J + jj) * 512 + g4s * 8;
        dstB[j] = BOFF + (uint32_t)e * 1024;
    }
    // hA staging lane offsets (row r = w*16+j)
    uint32_t srcAoff[16];
    #pragma unroll
    for (int j = 0; j < 16; j++) {
        int r = w * 16 + j;
        srcAoff[j] = (uint32_t)((lane ^ (r & 7)) * 8);
    }

    for (int t = 0; t < 12; t++) {
        const _Float16* hin = (t & 1) ? h16b : h16a;
        _Float16* hout = (t & 1) ? h16a : h16b;

        // stage hA (64 rows x 512) + B chunk 0
        #pragma unroll
        for (int j = 0; j < 16; j++) {
            int r = w * 16 + j;
            async16(smem + HA + (uint32_t)r * 1024, hin + (size_t)(R + r) * 512 + srcAoff[j]);
        }
        #pragma unroll
        for (int j = 0; j < 6; j++) async16(smem + dstB[j], srcB[j]);

        // prologue: x_t for this block's 64 rows (and write out_{t-1})
        if (tid < 128) {
            int iloc = tid >> 1, d = tid & 1;
            int i = R + iloc;
            float v;
            if (t == 0) {
                v = xbuf[(size_t)i * 2 + d];
            } else {
                const float4* p = (const float4*)(partial + (size_t)((t - 1) & 1) * 32768
                                                  + ((size_t)i * 2 + d) * 4);
                float4 a = *p;
                v = b_out[d] + a.x + a.y + a.z + a.w;
                if (ng == 0) dout[((size_t)i * 12 + (t - 1)) * 2 + d] = v;
            }
            xs[iloc * 2 + d] = v;
        }
        __syncthreads();   // hA + B0 staged, xs published

        floatx16 acc[2][3];
        #pragma unroll
        for (int mf = 0; mf < 2; mf++)
            #pragma unroll
            for (int g = 0; g < 3; g++)
                acc[mf][g] = (floatx16){0,0,0,0,0,0,0,0,0,0,0,0,0,0,0,0};

        uint32_t abase0 = HA + (uint32_t)(l31) * 1024;
        uint32_t abase1 = HA + (uint32_t)(32 + l31) * 1024;
        int aswz = l31 & 7;
        uint32_t bswz3 = (uint32_t)((l31 >> 1) & 3);
        uint32_t brow = (uint32_t)(w * 32 + l31) * 64;

        for (int c = 0; c < 16; c++) {
            if (c < 15) {
                uint32_t bb = BOFF + (uint32_t)((c + 1) & 1) * 24576;
                #pragma unroll
                for (int j = 0; j < 6; j++)
                    async16(smem + (dstB[j] - BOFF) + bb, srcB[j] + (c + 1) * 32);
            }
            uint32_t bbase = BOFF + (uint32_t)(c & 1) * 24576;
            #pragma unroll
            for (int ks2 = 0; ks2 < 2; ks2++) {
                int ks = c * 2 + ks2;
                uint32_t asw = (uint32_t)((2 * ks + half) ^ aswz) << 4;
                f16x8 a0 = *(const f16x8*)(smem + abase0 + asw);
                f16x8 a1 = *(const f16x8*)(smem + abase1 + asw);
                uint32_t g4 = (uint32_t)(ks2 * 2 + half);
                uint32_t bsw = ((g4 ^ bswz3) << 4);
                f16x8 b0 = *(const f16x8*)(smem + bbase + brow + bsw);
                f16x8 b1 = *(const f16x8*)(smem + bbase + 8192 + brow + bsw);
                f16x8 b2 = *(const f16x8*)(smem + bbase + 16384 + brow + bsw);
                acc[0][0] = __builtin_amdgcn_mfma_f32_32x32x16_f16(a0, b0, acc[0][0], 0, 0, 0);
                acc[0][1] = __builtin_amdgcn_mfma_f32_32x32x16_f16(a0, b1, acc[0][1], 0, 0, 0);
                acc[0][2] = __builtin_amdgcn_mfma_f32_32x32x16_f16(a0, b2, acc[0][2], 0, 0, 0);
                acc[1][0] = __builtin_amdgcn_mfma_f32_32x32x16_f16(a1, b0, acc[1][0], 0, 0, 0);
                acc[1][1] = __builtin_amdgcn_mfma_f32_32x32x16_f16(a1, b1, acc[1][1], 0, 0, 0);
                acc[1][2] = __builtin_amdgcn_mfma_f32_32x32x16_f16(a1, b2, acc[1][2], 0, 0, 0);
            }
            __syncthreads();   // next B chunk staged; this buf free for reuse
        }

        // epilogue: gates + state update + out-partial shuffle reduce
        #pragma unroll
        for (int mf = 0; mf < 2; mf++) {
            #pragma unroll
            for (int reg = 0; reg < 16; reg++) {
                int iloc = mf * 32 + (reg & 3) + 8 * (reg >> 2) + 4 * half;
                size_t i = (size_t)(R + iloc);
                const float* gi = gi2 + (i * 512 + jcg) * 3;
                float g0 = gi[0], g1 = gi[1], g2v = gi[2];
                float x0 = xs[iloc * 2], x1 = xs[iloc * 2 + 1];
                float hold = (float)(*(const _Float16*)(smem + HA + (uint32_t)iloc * 1024
                                   + (uint32_t)(((jcg >> 3) ^ (iloc & 7)) << 4) + (jcg & 7) * 2));
                float r = sigm_f(g0 + p0.x * x0 + p0.y * x1 + acc[mf][0][reg] + p1.z);
                float u = sigm_f(g1 + p0.z * x0 + p0.w * x1 + acc[mf][1][reg] + p1.w);
                float nn = tanh_f(g2v + p1.x * x0 + p1.y * x1 + r * (acc[mf][2][reg] + p2.x));
                float hn = (1.f - u) * nn + u * hold;
                hout[i * 512 + jcg] = (_Float16)hn;
                float q0 = hn * p2.y, q1 = hn * p2.z;
                #pragma unroll
                for (int off = 1; off < 32; off <<= 1) {
                    q0 += __shfl_xor(q0, off);
                    q1 += __shfl_xor(q1, off);
                }
                if (l31 == 0) {
                    part4[(iloc * 2 + 0) * 4 + w] = q0;
                    part4[(iloc * 2 + 1) * 4 + w] = q1;
                }
            }
        }
        __syncthreads();
        if (tid < 128) {
            int iloc = tid >> 1, d = tid & 1;
            int i = R + iloc;
            const float* pp = &part4[(iloc * 2 + d) * 4];
            partial[(size_t)(t & 1) * 32768 + ((size_t)i * 2 + d) * 4 + ng]
                = pp[0] + pp[1] + pp[2] + pp[3];
        }
        grid_barrier(grp, root, t, bid);
    }

    // final: out_11
    if (ng == 0 && tid < 128) {
        int iloc = tid >> 1, d = tid & 1;
        int i = R + iloc;
        const float4* p = (const float4*)(partial + 32768 + ((size_t)i * 2 + d) * 4);
        float4 a = *p;
        dout[((size_t)i * 12 + 11) * 2 + d] = b_out[d] + a.x + a.y + a.z + a.w;
    }
}

extern "C" void kernel_launch(void* const* d_in, const int* in_sizes, int n_in,
                              void* d_out, int out_size, void* d_ws, size_t ws_size,
                              hipStream_t stream)
{
    const float* z     = (const float*)d_in[0];
    const float* x     = (const float*)d_in[1];
    const float* x0    = (const float*)d_in[2];
    const float* W_ia  = (const float*)d_in[3];
    const float* b_ia  = (const float*)d_in[4];
    const float* W_h0  = (const float*)d_in[5];
    const float* b_h0  = (const float*)d_in[6];
    const float* W_ih  = (const float*)d_in[7];
    const float* b_ih  = (const float*)d_in[8];
    const float* W_hh  = (const float*)d_in[9];
    const float* b_hh  = (const float*)d_in[10];
    const float* W_out = (const float*)d_in[11];
    const float* b_out = (const float*)d_in[12];
    float* dout = (float*)d_out;

    char* ws = (char*)d_ws;
    _Float16* h16a   = (_Float16*)(ws + 0);          // 4096*512*2 = 4 MiB
    _Float16* h16b   = (_Float16*)(ws + 4194304);
    float*    gi2    = (float*)(ws + 8388608);       // 4096*512*3*4 = 24 MiB
    _Float16* zx16   = (_Float16*)(ws + 33554432);   // 2 MiB
    _Float16* wcat16 = (_Float16*)(ws + 35651584);   // 1 MiB
    _Float16* whh16  = (_Float16*)(ws + 36700160);   // 1.5 MiB
    float*    pk     = (float*)(ws + 38273024);      // 24 KiB
    float*    xbuf   = (float*)(ws + 38297600);      // 32 KiB
    float*    partial= (float*)(ws + 38330368);      // 2*32768 floats = 256 KiB
    unsigned* bars   = (unsigned*)(ws + 38592512);   // 12*16+12 counters

    hipMemsetAsync(bars, 0, 1024, stream);
    hipFuncSetAttribute((const void*)k2_all,
                        hipFuncAttributeMaxDynamicSharedMemorySize, 117248);

    k0_prep<<<2048, 256, 0, stream>>>(z, x, x0, W_ia, b_ia, W_ih, W_hh, W_h0,
                                      W_out, b_hh, zx16, wcat16, whh16, pk, xbuf);
    k1_precompute<<<dim3(32, 32), 256, 0, stream>>>(zx16, wcat16, b_h0, b_ih, h16a, gi2);
    k2_all<<<256, 256, 117248, stream>>>(whh16, gi2, pk, xbuf, h16a, h16b,
                                         partial, dout, b_out, bars);
}

// Round 5
// 294.984 us; speedup vs baseline: 3.6682x; 3.6682x over previous
//
#include <hip/hip_runtime.h>
#include <cstdint>
#include <cstddef>

// RNNDec GRU rollout: N=4096, H=512, T=12. R5 = R2 structure (best) + fp16
// single-plane MFMA (validated in R4: absmax 0.0078) + gi_base as 3 fp16
// planes (halves the per-step HBM stream). No XCD swizzle (R3 regressed),
// no persistent kernel (R4 regressed), per-step launches.

typedef __attribute__((ext_vector_type(8))) _Float16 f16x8;
typedef __attribute__((ext_vector_type(16))) float floatx16;

__device__ __forceinline__ float sigm_f(float v) { return 1.0f / (1.0f + __expf(-v)); }
__device__ __forceinline__ float tanh_f(float v) { return 2.0f / (1.0f + __expf(-2.0f * v)) - 1.0f; }

__device__ __forceinline__ void async16(void* lds, const void* g) {
    __builtin_amdgcn_global_load_lds(
        (const __attribute__((address_space(1))) void*)g,
        (__attribute__((address_space(3))) void*)lds, 16, 0, 0);
}

// ---------------- K0: casts + packing + a0 ----------------
__global__ __launch_bounds__(256) void k0_prep(
    const float* __restrict__ z, const float* __restrict__ x,
    const float* __restrict__ x0, const float* __restrict__ W_ia,
    const float* __restrict__ b_ia, const float* __restrict__ W_ih,
    const float* __restrict__ W_hh, const float* __restrict__ W_h0,
    const float* __restrict__ W_out, const float* __restrict__ b_hh,
    _Float16* __restrict__ zx16, _Float16* __restrict__ wcat16,
    _Float16* __restrict__ whh16, float* __restrict__ pk, float* __restrict__ xbuf)
{
    const int ZX = 4096 * 256, WC = 2048 * 256, WH = 1536 * 512, PKN = 512, XB = 4096 * 2;
    const int total = ZX + WC + WH + PKN + XB;
    for (int idx = blockIdx.x * 256 + threadIdx.x; idx < total; idx += gridDim.x * 256) {
        if (idx < ZX) {
            int i = idx >> 8, k = idx & 255;
            float v = (k < 128) ? z[i * 128 + k] : x[i * 128 + (k - 128)];
            zx16[idx] = (_Float16)v;
        } else if (idx < ZX + WC) {
            int j = idx - ZX;
            int n = j >> 8, k = j & 255;
            float v = (n < 512) ? W_h0[n * 256 + k] : W_ih[(n - 512) * 258 + k];
            wcat16[j] = (_Float16)v;
        } else if (idx < ZX + WC + WH) {
            int j = idx - ZX - WC;
            whh16[j] = (_Float16)W_hh[j];
        } else if (idx < ZX + WC + WH + PKN) {
            int jc = idx - ZX - WC - WH;
            float* o = pk + jc * 12;
            o[0] = W_ih[jc * 258 + 256];          o[1] = W_ih[jc * 258 + 257];
            o[2] = W_ih[(512 + jc) * 258 + 256];  o[3] = W_ih[(512 + jc) * 258 + 257];
            o[4] = W_ih[(1024 + jc) * 258 + 256]; o[5] = W_ih[(1024 + jc) * 258 + 257];
            o[6] = b_hh[jc]; o[7] = b_hh[512 + jc]; o[8] = b_hh[1024 + jc];
            o[9] = W_out[jc]; o[10] = W_out[512 + jc]; o[11] = 0.f;
        } else {
            int j = idx - ZX - WC - WH - PKN;
            int i = j >> 1, d = j & 1;
            float s = b_ia[d];
            #pragma unroll
            for (int k2 = 0; k2 < 4; k2++) s += x0[i * 4 + k2] * W_ia[d * 4 + k2];
            xbuf[j] = s;
        }
    }
}

// ---------------- K1: h0 (cols 0..511) + gi planes (cols 512..2047), fp16 ----------------
// C[4096 x 2048] = zx16 @ wcat16^T, K=256. Tile 128m x 64n, BK=64, 4 chunks.
__global__ __launch_bounds__(256) void k1_precompute(
    const _Float16* __restrict__ zx16, const _Float16* __restrict__ wcat16,
    const float* __restrict__ b_h0, const float* __restrict__ b_ih,
    _Float16* __restrict__ h16a, _Float16* __restrict__ gi16)
{
    __shared__ __align__(16) char smem[24576];
    const uint32_t BOFF = 0, AOFF = 8192;
    int tid = threadIdx.x;
    int w = tid >> 6, lane = tid & 63;
    int half = lane >> 5, l31 = lane & 31;
    int rsub = lane >> 3, csub = lane & 7;
    int Mb = blockIdx.x * 128, Nb = blockIdx.y * 64;

    const _Float16* gsrc[6];
    uint32_t ldso[6];
    #pragma unroll
    for (int j = 0; j < 6; j++) {
        int L = w + 4 * j;
        if (L < 16) {
            int r = L * 8 + rsub;
            gsrc[j] = zx16 + (size_t)(Mb + r) * 256 + ((csub ^ (r & 7)) << 3);
            ldso[j] = AOFF + (uint32_t)L * 1024;
        } else {
            int rb = (L - 16) * 8 + rsub;
            gsrc[j] = wcat16 + (size_t)(Nb + rb) * 256 + ((csub ^ (rb & 7)) << 3);
            ldso[j] = BOFF + (uint32_t)(L - 16) * 1024;
        }
    }

    floatx16 acc0 = {0,0,0,0,0,0,0,0,0,0,0,0,0,0,0,0};
    floatx16 acc1 = {0,0,0,0,0,0,0,0,0,0,0,0,0,0,0,0};

    for (int kc = 0; kc < 4; kc++) {
        #pragma unroll
        for (int j = 0; j < 6; j++) async16(smem + ldso[j], gsrc[j] + kc * 64);
        __syncthreads();
        #pragma unroll
        for (int ks = 0; ks < 4; ks++) {
            int ch = ks * 2 + half;
            int ar = (w << 5) | l31;
            f16x8 a = *(const f16x8*)(smem + AOFF + ((uint32_t)ar << 7) + ((uint32_t)(ch ^ (ar & 7)) << 4));
            uint32_t sw = (uint32_t)(ch ^ (l31 & 7)) << 4;
            f16x8 b0 = *(const f16x8*)(smem + BOFF + ((uint32_t)l31 << 7) + sw);
            f16x8 b1 = *(const f16x8*)(smem + BOFF + ((uint32_t)(32 + l31) << 7) + sw);
            acc0 = __builtin_amdgcn_mfma_f32_32x32x16_f16(a, b0, acc0, 0, 0, 0);
            acc1 = __builtin_amdgcn_mfma_f32_32x32x16_f16(a, b1, acc1, 0, 0, 0);
        }
        __syncthreads();
    }

    #pragma unroll
    for (int nt = 0; nt < 2; nt++) {
        int ncol = Nb + nt * 32 + l31;
        floatx16 acc = nt ? acc1 : acc0;
        #pragma unroll
        for (int reg = 0; reg < 16; reg++) {
            int row = (reg & 3) + 8 * (reg >> 2) + 4 * half;
            size_t i = (size_t)Mb + (w << 5) + row;
            float v = acc[reg];
            if (ncol < 512) {
                h16a[i * 512 + ncol] = (_Float16)(v + b_h0[ncol]);
            } else {
                int c = ncol - 512;
                int g = c >> 9, jc = c & 511;
                gi16[(size_t)g * 2097152 + i * 512 + jc] = (_Float16)(v + b_ih[c]);
            }
        }
    }
}

// ---------------- K2: one GRU step (R2 structure, fp16) ----------------
// Tile 128m x (32 jc x 3 gates). grid (32,16), 256 thr = 4 waves.
__global__ __launch_bounds__(256) void k2_step(
    int t,
    const _Float16* __restrict__ hin, _Float16* __restrict__ hout,
    const _Float16* __restrict__ whh16, const _Float16* __restrict__ gi16,
    const float* __restrict__ pk, const float* __restrict__ xbuf,
    float* __restrict__ partial, float* __restrict__ dout,
    const float* __restrict__ b_out)
{
    __shared__ __align__(16) char smem[46080];
    const uint32_t BOFF = 0, AOFF = 12288, PROD = 12288, XS = 45056;
    int tid = threadIdx.x;
    int bx = blockIdx.x, by = blockIdx.y;
    int Mbase = bx * 128, Jbase = by * 32;
    int w = tid >> 6, lane = tid & 63;
    int half = lane >> 5, l31 = lane & 31;
    int rsub = lane >> 3, csub = lane & 7;
    float* xs = (float*)(smem + XS);  // [128][2]

    // staging: A = 16 slots of 8 rows x 64 fp16; B = 12 slots (96 rows: g*32+jin)
    const _Float16* gsrc[7];
    uint32_t ldso[7];
    #pragma unroll
    for (int j = 0; j < 7; j++) {
        int L = w + 4 * j;   // 0..27
        if (L < 16) {
            int r = L * 8 + rsub;
            gsrc[j] = hin + (size_t)(Mbase + r) * 512 + ((csub ^ (r & 7)) << 3);
            ldso[j] = AOFF + (uint32_t)L * 1024;
        } else {
            int rb = (L - 16) * 8 + rsub;   // 0..95: rb = g*32 + jin
            int g = rb >> 5, jin = rb & 31;
            gsrc[j] = whh16 + (size_t)(g * 512 + Jbase + jin) * 512 + ((csub ^ (rb & 7)) << 3);
            ldso[j] = BOFF + (uint32_t)(L - 16) * 1024;
        }
    }

    // prologue: x_t for this block's 128 samples (and write out_{t-1})
    {
        int i = tid >> 1, d = tid & 1;
        float v;
        if (t == 0) {
            v = xbuf[(size_t)(Mbase + i) * 2 + d];
        } else {
            const float4* p = (const float4*)(partial + ((size_t)(Mbase + i) * 2 + d) * 16);
            float4 a = p[0], b = p[1], c = p[2], e = p[3];
            v = b_out[d] + a.x + a.y + a.z + a.w + b.x + b.y + b.z + b.w
                         + c.x + c.y + c.z + c.w + e.x + e.y + e.z + e.w;
            if (by == 0) dout[((size_t)(Mbase + i) * 12 + (t - 1)) * 2 + d] = v;
        }
        xs[i * 2 + d] = v;
    }

    floatx16 accR = {0,0,0,0,0,0,0,0,0,0,0,0,0,0,0,0};
    floatx16 accZ = {0,0,0,0,0,0,0,0,0,0,0,0,0,0,0,0};
    floatx16 accN = {0,0,0,0,0,0,0,0,0,0,0,0,0,0,0,0};

    for (int kc = 0; kc < 8; kc++) {
        #pragma unroll
        for (int j = 0; j < 7; j++) async16(smem + ldso[j], gsrc[j] + kc * 64);
        __syncthreads();
        #pragma unroll
        for (int ks = 0; ks < 4; ks++) {
            int ch = ks * 2 + half;
            int ar = (w << 5) | l31;
            f16x8 a = *(const f16x8*)(smem + AOFF + ((uint32_t)ar << 7) + ((uint32_t)(ch ^ (ar & 7)) << 4));
            uint32_t sw = (uint32_t)(ch ^ (l31 & 7)) << 4;
            f16x8 b0 = *(const f16x8*)(smem + BOFF + ((uint32_t)l31 << 7) + sw);
            f16x8 b1 = *(const f16x8*)(smem + BOFF + ((uint32_t)(32 + l31) << 7) + sw);
            f16x8 b2 = *(const f16x8*)(smem + BOFF + ((uint32_t)(64 + l31) << 7) + sw);
            accR = __builtin_amdgcn_mfma_f32_32x32x16_f16(a, b0, accR, 0, 0, 0);
            accZ = __builtin_amdgcn_mfma_f32_32x32x16_f16(a, b1, accZ, 0, 0, 0);
            accN = __builtin_amdgcn_mfma_f32_32x32x16_f16(a, b2, accN, 0, 0, 0);
        }
        __syncthreads();
    }

    // epilogue: gates + state update; out-partials in LDS (reuse A/B region)
    float* prod = (float*)(smem + PROD);  // [128][32][2] fp32 = 32 KB
    int jcg = Jbase + l31;
    const float4* pkp = (const float4*)(pk + (size_t)jcg * 12);
    float4 p0 = pkp[0], p1 = pkp[1], p2 = pkp[2];
    // p0={wxr0,wxr1,wxz0,wxz1} p1={wxn0,wxn1,bhr,bhz} p2={bhn,wo0,wo1,-}
    const _Float16* giR = gi16;
    const _Float16* giZ = gi16 + 2097152;
    const _Float16* giN = gi16 + 4194304;
    #pragma unroll
    for (int reg = 0; reg < 16; reg++) {
        int row = (reg & 3) + 8 * (reg >> 2) + 4 * half;
        int iloc = (w << 5) + row;
        size_t i = (size_t)Mbase + iloc;
        float g0 = (float)giR[i * 512 + jcg];
        float g1 = (float)giZ[i * 512 + jcg];
        float g2v = (float)giN[i * 512 + jcg];
        float x0 = xs[iloc * 2], x1 = xs[iloc * 2 + 1];
        float r = sigm_f(g0 + p0.x * x0 + p0.y * x1 + accR[reg] + p1.z);
        float u = sigm_f(g1 + p0.z * x0 + p0.w * x1 + accZ[reg] + p1.w);
        float nn = tanh_f(g2v + p1.x * x0 + p1.y * x1 + r * (accN[reg] + p2.x));
        float hold = (float)hin[i * 512 + jcg];
        float hn = (1.f - u) * nn + u * hold;
        hout[i * 512 + jcg] = (_Float16)hn;
        ((float2*)prod)[iloc * 32 + l31] = make_float2(hn * p2.y, hn * p2.z);
    }
    __syncthreads();
    {
        int i = tid >> 1, d = tid & 1;
        float s = 0.f;
        #pragma unroll
        for (int jj = 0; jj < 32; jj++) {
            int jc = (jj + i) & 31;   // skew to avoid bank conflicts
            s += prod[(i * 32 + jc) * 2 + d];
        }
        partial[((size_t)(Mbase + i) * 2 + d) * 16 + by] = s;
    }
}

// ---------------- K3: final output out_11 ----------------
__global__ __launch_bounds__(256) void k3_final(
    const float* __restrict__ partial, const float* __restrict__ b_out,
    float* __restrict__ dout)
{
    int gid = blockIdx.x * 256 + threadIdx.x;
    if (gid < 8192) {
        int i = gid >> 1, d = gid & 1;
        const float4* p = (const float4*)(partial + ((size_t)i * 2 + d) * 16);
        float4 a = p[0], b = p[1], c = p[2], e = p[3];
        float v = b_out[d] + a.x + a.y + a.z + a.w + b.x + b.y + b.z + b.w
                           + c.x + c.y + c.z + c.w + e.x + e.y + e.z + e.w;
        dout[((size_t)i * 12 + 11) * 2 + d] = v;
    }
}

extern "C" void kernel_launch(void* const* d_in, const int* in_sizes, int n_in,
                              void* d_out, int out_size, void* d_ws, size_t ws_size,
                              hipStream_t stream)
{
    const float* z     = (const float*)d_in[0];
    const float* x     = (const float*)d_in[1];
    const float* x0    = (const float*)d_in[2];
    const float* W_ia  = (const float*)d_in[3];
    const float* b_ia  = (const float*)d_in[4];
    const float* W_h0  = (const float*)d_in[5];
    const float* b_h0  = (const float*)d_in[6];
    const float* W_ih  = (const float*)d_in[7];
    const float* b_ih  = (const float*)d_in[8];
    const float* W_hh  = (const float*)d_in[9];
    const float* b_hh  = (const float*)d_in[10];
    const float* W_out = (const float*)d_in[11];
    const float* b_out = (const float*)d_in[12];
    float* dout = (float*)d_out;

    char* ws = (char*)d_ws;
    _Float16* h16a   = (_Float16*)(ws + 0);          // 4 MiB
    _Float16* h16b   = (_Float16*)(ws + 4194304);    // 4 MiB
    _Float16* gi16   = (_Float16*)(ws + 8388608);    // 3 planes x 4096*512 fp16 = 12 MiB
    _Float16* zx16   = (_Float16*)(ws + 20971520);   // 2 MiB
    _Float16* wcat16 = (_Float16*)(ws + 23068672);   // 1 MiB
    _Float16* whh16  = (_Float16*)(ws + 24117248);   // 1.5 MiB
    float*    pk     = (float*)(ws + 25690112);      // 24 KiB
    float*    xbuf   = (float*)(ws + 25714688);      // 32 KiB
    float*    partial= (float*)(ws + 25747456);      // 512 KiB

    k0_prep<<<2048, 256, 0, stream>>>(z, x, x0, W_ia, b_ia, W_ih, W_hh, W_h0,
                                      W_out, b_hh, zx16, wcat16, whh16, pk, xbuf);
    k1_precompute<<<dim3(32, 32), 256, 0, stream>>>(zx16, wcat16, b_h0, b_ih, h16a, gi16);
    for (int t = 0; t < 12; t++) {
        _Float16* hin  = (t & 1) ? h16b : h16a;
        _Float16* hout = (t & 1) ? h16a : h16b;
        k2_step<<<dim3(32, 16), 256, 0, stream>>>(t, hin, hout, whh16, gi16,
                                                  pk, xbuf, partial, dout, b_out);
    }
    k3_final<<<32, 256, 0, stream>>>(partial, b_out, dout);
}